// Round 7
// baseline (101.772 us; speedup 1.0000x reference)
//
#include <hip/hip_runtime.h>
#include <stdint.h>

// FFM: B=4096, F=20 fields x S=500 feats, K=16.
// E2[b, i*336 + g*16 + k] = sum_s x[b,i*500+s]*v[g,i*500+s,k]  (g<20)
// E2[b, i*336 + 320]      = sum_s x[b,i*500+s]*w[i*500+s]      (linear partial)
// out[b] = sum_i E2[b,i,320] + sum_{i<j,k} E2[b,i*336+j*16+k]*E2[b,j*336+i*16+k]

#define NF 20
#define FS 500
#define TFEAT 10000
#define KD 16
#define NCOL 336        // 21 frags: 320 interaction cols + 16-col w block
#define NFRG 21
#define KP 512
#define NB 4096
#define ROWE (NF * NCOL)  // 6720

typedef __bf16 bf16x8 __attribute__((ext_vector_type(8)));
typedef __bf16 bf16x2 __attribute__((ext_vector_type(2)));
typedef float  f32x4  __attribute__((ext_vector_type(4)));
typedef unsigned int u32x4 __attribute__((ext_vector_type(4)));

typedef __attribute__((address_space(1))) const void* as1cv;
typedef __attribute__((address_space(3))) void* as3v;

__device__ inline void gload_lds16(const void* g, void* l) {
  __builtin_amdgcn_global_load_lds((as1cv)g, (as3v)l, 16, 0, 0);
}

// ---------------- prep: Vt[i][n][kk], n<336: n=g*16+k -> v[g,i*500+kk,k]; n=320 -> w; rest 0
__global__ __launch_bounds__(256) void prep_vt(const float* __restrict__ v,
                                               const float* __restrict__ w,
                                               __bf16* __restrict__ Vt) {
  const int i = blockIdx.x / (NF + 1);
  const int g = blockIdx.x % (NF + 1);
  const int t = threadIdx.x;
  if (g == NF) {  // w block: rows 320..335
    const float* wf = w + (size_t)i * FS;
    __bf16* o = Vt + ((size_t)i * NCOL + 320) * KP;
    for (int idx = t; idx < 16 * KP; idx += 256) {
      int r = idx >> 9, kk = idx & (KP - 1);
      __bf16 val = (__bf16)0.f;
      if (r == 0 && kk < FS) val = (__bf16)wf[kk];
      o[(size_t)r * KP + kk] = val;
    }
    return;
  }
  __shared__ float lv[FS * 17];
  const int k = t & 15, sb = t >> 4;
  const float* vb = v + ((size_t)g * TFEAT + (size_t)i * FS) * KD;
  for (int it = 0; it < 32; ++it) {
    int s = it * 16 + sb;
    if (s < FS) lv[s * 17 + k] = vb[(size_t)s * KD + k];
  }
  __syncthreads();
  __bf16* out = Vt + ((size_t)i * NCOL + g * 16) * KP;
  for (int r = 0; r < 16; ++r) {
    int s0 = 2 * t, s1 = 2 * t + 1;
    bf16x2 pr;
    pr[0] = (s0 < FS) ? (__bf16)lv[s0 * 17 + r] : (__bf16)0.f;
    pr[1] = (s1 < FS) ? (__bf16)lv[s1 * 17 + r] : (__bf16)0.f;
    *(bf16x2*)(out + (size_t)r * KP + 2 * t) = pr;
  }
}

// ---------------- K1: per-field GEMM. BM=64, BN=336, BK=32, 16 steps, 4 waves.
// A: reg ping-pong prefetch DISTANCE 2 (iter t loads tile t+2 into set t&1;
//    astore writes set (t+1)&1, whose loads are ~1.7 iters old -> HBM covered).
// B: bf16 glds dbuf, issued FIRST each iter so end drain s_waitcnt vmcnt(2)
//    drains B but leaves the 2 newest A loads in flight (never vmcnt(0)).
// LDS 51.2 KB -> 3 blocks/CU. XOR swizzles as R6 (0 conflicts).
__global__ __launch_bounds__(256, 3) void k1_gemm(
    const float* __restrict__ x, const __bf16* __restrict__ Vt,
    __bf16* __restrict__ E2, int chunk_base, int tiles) {
  __shared__ __bf16 As[2][64][32];        // 8192 B
  __shared__ __bf16 Bs[2][NCOL * 32];     // 43008 B

  const int bx = blockIdx.x;
  const int i  = bx / tiles;
  const int tb = bx % tiles;
  const int tid = threadIdx.x;
  const int lane = tid & 63, wid = tid >> 6;
  const int b0 = chunk_base + tb * 64;

  // A stage (per thread): row = tid>>2, 8 cols at (tid&3)*8; swizzled chunk
  const int arow = tid >> 2;
  const int ac8 = (tid & 3) * 8;
  const int apch = (tid & 3) ^ ((tid >> 3) & 3);
  const float* xrow = x + (size_t)(b0 + arow) * TFEAT + i * FS;
  // B stage: instr q covers 16 rows x 4 chunks; src chunk pre-swizzled
  const int brow_off = lane >> 2;
  const int blc8 = ((lane & 3) ^ ((lane >> 3) & 3)) * 8;
  const __bf16* VtB = Vt + (size_t)i * NCOL * KP;

  auto issueB = [&](int t, int buf) {
    int soffB = t * 32 + blc8;
#pragma unroll
    for (int jj = 0; jj < 6; ++jj) {
      int q = wid + 4 * jj;
      if (q < NFRG)
        gload_lds16(VtB + (size_t)(16 * q + brow_off) * KP + soffB,
                    (void*)&Bs[buf][q * 16 * 32]);
    }
  };

  f32x4 a0A, a1A, a0B, a1B;   // two named prefetch sets (static indexing)
  auto aload = [&](int t, f32x4& r0, f32x4& r1) {
    int kk = t * 32 + ac8;
    int c0 = kk > 496 ? 496 : kk;          // clamp: junk cols pair with zero B rows
    int c1 = kk + 4 > 496 ? 496 : kk + 4;
    r0 = *(const f32x4*)(xrow + c0);
    r1 = *(const f32x4*)(xrow + c1);
  };
  auto astore = [&](int buf, const f32x4& r0, const f32x4& r1) {
    bf16x8 h;
    h[0] = (__bf16)r0[0]; h[1] = (__bf16)r0[1];
    h[2] = (__bf16)r0[2]; h[3] = (__bf16)r0[3];
    h[4] = (__bf16)r1[0]; h[5] = (__bf16)r1[1];
    h[6] = (__bf16)r1[2]; h[7] = (__bf16)r1[3];
    *(bf16x8*)(&As[buf][arow][apch * 8]) = h;
  };

  const int nfr = wid ? 5 : 6;
  const int Fbase = wid ? (1 + wid * 5) : 0;
  const int ar = lane & 15, akc = lane >> 4;

  f32x4 acc[4][6];
#pragma unroll
  for (int m = 0; m < 4; ++m)
#pragma unroll
    for (int nf = 0; nf < 6; ++nf) acc[m][nf] = (f32x4){0.f, 0.f, 0.f, 0.f};

  // prologue: tile0 -> As[0]; B(0) staged; tile1 regs (set1) left in flight
  aload(0, a0A, a1A);
  astore(0, a0A, a1A);            // waits its own loads (prologue only)
  issueB(0, 0);
  aload(1, a0B, a1B);             // newest: stays in flight across drain
  asm volatile("s_waitcnt vmcnt(2) lgkmcnt(0)" ::: "memory");
  __builtin_amdgcn_s_barrier();

  auto body = [&](int T, int curbuf, f32x4& la0, f32x4& la1,
                  f32x4& sa0, f32x4& sa1) {
    if (T < 15) issueB(T + 1, curbuf ^ 1);         // 6 glds (older)
    if (T < 14) aload(T + 2, la0, la1);            // 2 loads (newest, stay in flight)
    __builtin_amdgcn_sched_barrier(0);

    bf16x8 bfr[6];
#pragma unroll
    for (int nf = 0; nf < 6; ++nf)
      if (nf < nfr) {
        int n_ = (Fbase + nf) * 16 + ar;
        int pc = akc ^ ((n_ >> 1) & 3);
        bfr[nf] = *(const bf16x8*)&Bs[curbuf][n_ * 32 + pc * 8];
      }
#pragma unroll
    for (int m = 0; m < 4; ++m) {
      int row = m * 16 + ar;
      int pch = akc ^ ((row >> 1) & 3);
      bf16x8 af = *(const bf16x8*)(&As[curbuf][row][pch * 8]);
#pragma unroll
      for (int nf = 0; nf < 6; ++nf)
        if (nf < nfr)
          acc[m][nf] = __builtin_amdgcn_mfma_f32_16x16x32_bf16(af, bfr[nf],
                                                               acc[m][nf], 0, 0, 0);
    }
    if (T < 15) {
      astore(curbuf ^ 1, sa0, sa1);    // regs ~1.7 iters old; wait ~free
      if (T < 14)
        asm volatile("s_waitcnt vmcnt(2) lgkmcnt(0)" ::: "memory");  // counted
      else
        asm volatile("s_waitcnt vmcnt(0) lgkmcnt(0)" ::: "memory");  // tail
      __builtin_amdgcn_s_barrier();
    }
  };

  for (int tt = 0; tt < 16; tt += 2) {
    body(tt,     0, a0A, a1A, a0B, a1B);   // load set0 (tile tt+2), store set1
    body(tt + 1, 1, a0B, a1B, a0A, a1A);   // load set1 (tile tt+3), store set0
  }

  // epilogue: C/D layout col=lane&15, row=(lane>>4)*4+r
  const int lr4 = (lane >> 4) * 4, lcol = lane & 15;
#pragma unroll
  for (int m = 0; m < 4; ++m)
#pragma unroll
    for (int nf = 0; nf < 6; ++nf)
      if (nf < nfr) {
        int n = (Fbase + nf) * 16 + lcol;
#pragma unroll
        for (int r = 0; r < 4; ++r) {
          int bl = tb * 64 + m * 16 + lr4 + r;
          E2[(size_t)bl * ROWE + i * NCOL + n] = (__bf16)acc[m][nf][r];
        }
      }
}

// ---------------- K2: pair + linear reduction, 1 wave per batch row
__global__ __launch_bounds__(256) void k2_pair(
    const __bf16* __restrict__ E2, float* __restrict__ out, int chunk_base) {
  __shared__ __align__(16) unsigned shw[4][3360];  // 13440 B per wave
  const int tid = threadIdx.x, lane = tid & 63, wid = tid >> 6;
  const int bl = blockIdx.x * 4 + wid;
  const unsigned* src = (const unsigned*)(E2 + (size_t)bl * ROWE);
  for (int it = 0; it < 14; ++it) {
    int idx = it * 64 + lane;             // 16B units; 840 total
    if (idx < 840) {
      u32x4 val = *(const u32x4*)(src + (size_t)idx * 4);
      *(u32x4*)&shw[wid][idx * 4] = val;
    }
  }
  __syncthreads();
  const __bf16* sh = (const __bf16*)shw[wid];
  const int k = lane & 15, g = lane >> 4;
  float sum = 0.f;
  for (int i = g; i < NF; i += 4)
    for (int j = i + 1; j < NF; ++j)
      sum += (float)sh[i * NCOL + j * 16 + k] * (float)sh[j * NCOL + i * 16 + k];
  if (lane < NF) sum += (float)sh[lane * NCOL + 320];   // linear term
#pragma unroll
  for (int off = 32; off; off >>= 1) sum += __shfl_xor(sum, off);
  if (lane == 0) out[chunk_base + bl] = sum;
}

extern "C" void kernel_launch(void* const* d_in, const int* in_sizes, int n_in,
                              void* d_out, int out_size, void* d_ws, size_t ws_size,
                              hipStream_t stream) {
  const float* x = (const float*)d_in[0];
  const float* w = (const float*)d_in[1];
  const float* v = (const float*)d_in[2];
  float* out = (float*)d_out;
  char* ws = (char*)d_ws;

  const size_t vt_bytes = (size_t)NF * NCOL * KP * 2;   // 6,881,280
  __bf16* Vt = (__bf16*)ws;
  __bf16* E2 = (__bf16*)(ws + vt_bytes);

  size_t eavail = (ws_size > vt_bytes) ? ws_size - vt_bytes : 0;
  int Bc = NB;
  while (Bc > 64 && (size_t)Bc * ROWE * 2 > eavail) Bc >>= 1;

  prep_vt<<<NF * (NF + 1), 256, 0, stream>>>(v, w, Vt);
  for (int cb = 0; cb < NB; cb += Bc) {
    int tiles = Bc / 64;
    k1_gemm<<<NF * tiles, 256, 0, stream>>>(x, Vt, E2, cb, tiles);
    k2_pair<<<Bc / 4, 256, 0, stream>>>(E2, out, cb);
  }
}